// Round 8
// baseline (145.494 us; speedup 1.0000x reference)
//
#include <hip/hip_runtime.h>

typedef unsigned int uint;

#define B_ 2
#define C_ 128
#define H_ 96
#define W_ 96
#define HEADS_ 4
#define HD_ 32
#define M_ 16
#define WIN_ 7
#define PAD_ 3
#define N_ (H_*W_)              // 9216
#define HP_ (H_+2*PAD_)         // 102
#define HP2_ (HP_*HP_)          // 10404
#define KW_ (WIN_*WIN_)         // 49
#define TILE_ 8                 // attn tile is 8x8 pixels
#define HALO_ (TILE_+WIN_-1)    // 14
#define NHALO_ (HALO_*HALO_)    // 196

static __device__ __forceinline__ uint f2bf(float f) {
    uint u = __float_as_uint(f);
    u = (u + 0x7fffu + ((u >> 16) & 1u)) >> 16;   // RNE to bf16
    return u & 0xffffu;
}
static __device__ __forceinline__ uint pack2(float a, float b) {
    return f2bf(a) | (f2bf(b) << 16);
}
static __device__ __forceinline__ float bf_lo(uint u){ return __uint_as_float(u << 16); }
static __device__ __forceinline__ float bf_hi(uint u){ return __uint_as_float(u & 0xffff0000u); }

// inline function, not a macro: macro params named w/x/y/z collide with
// float4 member access under preprocessor substitution.
static __device__ __forceinline__ void fma4(float4& acc, float s, const float4& v) {
    acc.x = fmaf(s, v.x, acc.x);
    acc.y = fmaf(s, v.y, acc.y);
    acc.z = fmaf(s, v.z, acc.z);
    acc.w = fmaf(s, v.w, acc.w);
}

// Intra-quad cross-lane via DPP quad_perm (VALU pipe) instead of __shfl_*.
template<int CTRL>
static __device__ __forceinline__ float dpp_mov(float v) {
    return __int_as_float(__builtin_amdgcn_update_dpp(
        0, __float_as_int(v), CTRL, 0xF, 0xF, false));
}
#define DPP_XOR1(v)  dpp_mov<0xB1>(v)   // [1,0,3,2]
#define DPP_XOR2(v)  dpp_mov<0x4E>(v)   // [2,3,0,1]
#define DPP_BCAST0(v) dpp_mov<0x00>(v)
#define DPP_BCAST1(v) dpp_mov<0x55>(v)
#define DPP_BCAST2(v) dpp_mov<0xAA>(v)
#define DPP_BCAST3(v) dpp_mov<0xFF>(v)

// ---------------------------------------------------------------------------
// KVp layout (head-major, K/V interleaved, bf16 pairs):
//   KVp[((b*HEADS+h)*HP2 + row)*32 + u], u<16: K pair u, u>=16: V pair u-16.
// ---------------------------------------------------------------------------

// Kernel 1: fill padded borders of KVp with bias (= proj of zero input), and
// build PhiT: [B][102][102][16] fp32, border = 1.0
__global__ __launch_bounds__(256) void pad_fill(
    const float* __restrict__ phi, const float* __restrict__ bk, const float* __restrict__ bv,
    uint* __restrict__ KVp, float* __restrict__ PhiT)
{
    int idx = blockIdx.x * 256 + threadIdx.x;
    if (idx >= B_*HP2_) return;
    int b  = idx / HP2_;
    int pp = idx % HP2_;
    int py = pp / HP_, px = pp % HP_;
    bool interior = (py >= PAD_ && py < H_+PAD_ && px >= PAD_ && px < W_+PAD_);
    if (!interior) {
        #pragma unroll
        for (int h = 0; h < HEADS_; ++h) {
            size_t base = ((size_t)(b*HEADS_+h)*HP2_ + pp) * 32;
            #pragma unroll
            for (int q4i = 0; q4i < 4; ++q4i) {
                const float* kb8 = bk + h*HD_ + q4i*8;
                const float* vb8 = bv + h*HD_ + q4i*8;
                uint4 ku, vu;
                ku.x = pack2(kb8[0],kb8[1]); ku.y = pack2(kb8[2],kb8[3]);
                ku.z = pack2(kb8[4],kb8[5]); ku.w = pack2(kb8[6],kb8[7]);
                vu.x = pack2(vb8[0],vb8[1]); vu.y = pack2(vb8[2],vb8[3]);
                vu.z = pack2(vb8[4],vb8[5]); vu.w = pack2(vb8[6],vb8[7]);
                ((uint4*)(KVp + base))[q4i]     = ku;
                ((uint4*)(KVp + base))[4 + q4i] = vu;
            }
        }
    }
    size_t pb = ((size_t)b*HP2_ + pp) * M_;
    if (interior) {
        int y = py - PAD_, xx = px - PAD_;
        #pragma unroll
        for (int m = 0; m < M_; ++m)
            PhiT[pb + m] = phi[((size_t)b*M_ + m)*N_ + y*W_ + xx];
    } else {
        #pragma unroll
        for (int m = 0; m < M_; ++m) PhiT[pb + m] = 1.0f;
    }
}

// ---------------------------------------------------------------------------
// Kernel 2: Q/K/V projection, one projection per block (grid.z = 0/1/2).
// ---------------------------------------------------------------------------
__global__ __launch_bounds__(256, 3) void qkv_proj(
    const float* __restrict__ x,
    const float* __restrict__ Wq, const float* __restrict__ bq,
    const float* __restrict__ Wk, const float* __restrict__ bk,
    const float* __restrict__ Wv, const float* __restrict__ bv,
    float* __restrict__ Qp, uint* __restrict__ KVp)
{
    __shared__ float4 ldsW4[64*32];   // 64 ci x 128 co (32 KB)
    __shared__ float4 ldsX4[128*8];   // [ci][pix] 128 x 32 (16 KB)

    const int t  = threadIdx.x;
    const int n0 = blockIdx.x * 32;
    const int b  = blockIdx.y;
    const int pj = blockIdx.z;
    const float* Wsrc = (pj == 0) ? Wq : (pj == 1) ? Wk : Wv;
    const float* bsrc = (pj == 0) ? bq : (pj == 1) ? bk : bv;

    for (int idx = t; idx < 128*32; idx += 256) {
        int pix = idx & 31, ci = idx >> 5;
        ((float*)ldsX4)[ci*32 + pix] = x[((size_t)b*C_ + ci)*N_ + n0 + pix];
    }

    const int co_g  = t & 31;   // co = co_g*4 .. +3
    const int pix_g = t >> 5;   // pix = pix_g*4 .. +3

    float4 bias = *(const float4*)(bsrc + co_g*4);
    float4 acc0 = bias, acc1 = bias, acc2 = bias, acc3 = bias;
    for (int half = 0; half < 2; ++half) {
        __syncthreads();   // guards x-stage (half 0) and ldsW readers (half 1)
        const float4* wsrc4 = (const float4*)(Wsrc + (size_t)half*64*C_);
        for (int idx = t; idx < 64*32; idx += 256) ldsW4[idx] = wsrc4[idx];
        __syncthreads();
        #pragma unroll 8
        for (int ci = 0; ci < 64; ++ci) {
            float4 xv = ldsX4[(half*64 + ci)*8 + pix_g];
            float4 wv = ldsW4[ci*32 + co_g];
            fma4(acc0, xv.x, wv);
            fma4(acc1, xv.y, wv);
            fma4(acc2, xv.z, wv);
            fma4(acc3, xv.w, wv);
        }
    }
    float4 accs[4] = {acc0, acc1, acc2, acc3};
    #pragma unroll
    for (int p = 0; p < 4; ++p) {
        int n = n0 + pix_g*4 + p;
        if (pj == 0) {
            *(float4*)(Qp + ((size_t)b*N_ + n)*C_ + co_g*4) = accs[p];
        } else {
            int y = n / W_, xx = n % W_;
            size_t rowb = (size_t)(y+PAD_)*HP_ + (xx+PAD_);
            int h = co_g >> 3;
            int u = ((pj == 1) ? 0 : 16) + (co_g & 7)*2;
            uint2 uu;
            uu.x = pack2(accs[p].x, accs[p].y);
            uu.y = pack2(accs[p].z, accs[p].w);
            *(uint2*)(KVp + ((size_t)(b*HEADS_+h)*HP2_ + rowb)*32 + u) = uu;
        }
    }
}

// ---------------------------------------------------------------------------
// Kernel 3: local attention, 4 threads per (pixel, head).
// K/V halo in LDS (24.5 KB -> 6 blocks/CU); phi read from GLOBAL (12.5 KB
// halo is L1-resident; moves 49 loads/thread from the LDS pipe to the idle
// vmem pipe). Fully macro-unrolled; intra-quad reduce via DPP.
// ---------------------------------------------------------------------------
__global__ __launch_bounds__(256, 5) void attn(
    const float* __restrict__ Qp, const uint* __restrict__ KVp,
    const float* __restrict__ PhiT, const float* __restrict__ log_alpha,
    const float* __restrict__ beta, float* __restrict__ AO)
{
    __shared__ uint4  kl[NHALO_*4];   // 12544 B
    __shared__ uint4  vl[NHALO_*4];   // 12544 B

    const int t  = threadIdx.x;
    const int h  = blockIdx.y;
    const int b  = blockIdx.z;
    const int bx = blockIdx.x;
    const int tile = ((bx & 7) * 18) + (bx >> 3);   // 144 = 8*18, bijective
    const int y0 = (tile / (W_/TILE_)) * TILE_;
    const int x0 = (tile % (W_/TILE_)) * TILE_;

    // stage K/V halo: one full 128B line per (row, head)
    const uint* kvb = KVp + (size_t)(b*HEADS_+h)*HP2_*32;
    for (int idx = t; idx < NHALO_*8; idx += 256) {
        int hp = idx >> 3, u4 = idx & 7;
        int hy = hp / HALO_, hx = hp % HALO_;
        size_t rowb = (size_t)(y0+hy)*HP_ + (x0+hx);
        uint4 val = *(const uint4*)(kvb + rowb*32 + u4*4);
        if (u4 < 4) kl[hp*4 + u4] = val;
        else        vl[hp*4 + (u4-4)] = val;
    }
    __syncthreads();

    const int s  = t & 3;       // sub-lane: channels s*8.., phi dims s*4..
    const int p  = t >> 2;      // pixel 0..63
    const int qy = p >> 3, qx = p & 7;
    const int n  = (y0+qy)*W_ + (x0+qx);
    const bool c1 = (s & 1) != 0;
    const bool c2 = (s & 2) != 0;

    float4 q0, q1;
    {
        const float* qptr = Qp + ((size_t)b*N_ + n)*C_ + h*HD_ + s*8;
        q0 = ((const float4*)qptr)[0];
        q1 = ((const float4*)qptr)[1];
    }
    // phi: center (exact) + window base pointer for this thread's quad slice
    const float* pwin = PhiT + ((size_t)b*HP2_ + (size_t)(y0+qy)*HP_ + (x0+qx))*M_ + s*4;
    float4 pc = *(const float4*)(pwin + ((size_t)PAD_*HP_ + PAD_)*M_);

    const float alpha = __expf(log_alpha[0]);
    const float scale = 0.17677669529663687f;                 // HD^-0.5
    const float gcoef = -beta[h] * alpha * 0.17677669529663687f; // -beta*alpha/sqrt(2M)

    auto partial = [&](int hp, const float4& pv) -> float {
        uint4 kw = kl[(hp<<2) + s];
        float4 acc = make_float4(0.f,0.f,0.f,0.f);
        acc.x = fmaf(q0.x, bf_lo(kw.x), acc.x);
        acc.y = fmaf(q0.y, bf_hi(kw.x), acc.y);
        acc.z = fmaf(q0.z, bf_lo(kw.y), acc.z);
        acc.w = fmaf(q0.w, bf_hi(kw.y), acc.w);
        acc.x = fmaf(q1.x, bf_lo(kw.z), acc.x);
        acc.y = fmaf(q1.y, bf_hi(kw.z), acc.y);
        acc.z = fmaf(q1.z, bf_lo(kw.w), acc.z);
        acc.w = fmaf(q1.w, bf_hi(kw.w), acc.w);
        float pdot = (acc.x + acc.y) + (acc.z + acc.w);
        float d0 = pc.x - pv.x, d1 = pc.y - pv.y;
        float d2 = pc.z - pv.z, d3 = pc.w - pv.w;
        float pdsq = fmaf(d0,d0, fmaf(d1,d1, fmaf(d2,d2, d3*d3)));
        return fmaf(pdot, scale, gcoef*pdsq);
    };

    float lp[13];
    float mx = -1e30f;

#define HPOS(KK) ((qy + (KK)/WIN_)*HALO_ + qx + ((KK)%WIN_))
#define PHV(KK) (*(const float4*)(pwin + (((KK)/WIN_)*HP_ + ((KK)%WIN_))*M_))
#define LGROUP(G) { \
    float pr0 = partial(HPOS(4*(G)  ), PHV(4*(G)  )); \
    float pr1 = partial(HPOS(4*(G)+1), PHV(4*(G)+1)); \
    float pr2 = partial(HPOS(4*(G)+2), PHV(4*(G)+2)); \
    float pr3 = partial(HPOS(4*(G)+3), PHV(4*(G)+3)); \
    float Av = (c1 ? pr1 : pr0) + DPP_XOR1(c1 ? pr0 : pr1); \
    float Bv = (c1 ? pr3 : pr2) + DPP_XOR1(c1 ? pr2 : pr3); \
    float lg = (c2 ? Bv : Av) + DPP_XOR2(c2 ? Av : Bv); \
    lp[(G)] = lg; mx = fmaxf(mx, lg); }

    LGROUP(0) LGROUP(1) LGROUP(2) LGROUP(3) LGROUP(4) LGROUP(5)
    LGROUP(6) LGROUP(7) LGROUP(8) LGROUP(9) LGROUP(10) LGROUP(11)
    {   // kk = 48: all lanes hold it; only lane s==0 "owns" it
        float pr = partial(HPOS(48), PHV(48));
        pr += DPP_XOR1(pr);
        pr += DPP_XOR2(pr);
        lp[12] = pr; mx = fmaxf(mx, pr);
    }
    mx = fmaxf(mx, DPP_XOR1(mx));
    mx = fmaxf(mx, DPP_XOR2(mx));

    float ssum = 0.f;
#define EXPG(G) { float e = __expf(lp[(G)] - mx); lp[(G)] = e; ssum += e; }
    EXPG(0) EXPG(1) EXPG(2) EXPG(3) EXPG(4) EXPG(5)
    EXPG(6) EXPG(7) EXPG(8) EXPG(9) EXPG(10) EXPG(11)
    {
        float e = (s == 0) ? __expf(lp[12] - mx) : 0.f;
        lp[12] = e; ssum += e;
    }
    ssum += DPP_XOR1(ssum);
    ssum += DPP_XOR2(ssum);
    float inv = 1.0f / ssum;

    float4 o0 = make_float4(0.f,0.f,0.f,0.f);
    float4 o1 = make_float4(0.f,0.f,0.f,0.f);
#define PVPOS(KK, BC) { \
    float wgt = DPP_BCAST##BC(lp[(KK)>>2]); \
    uint4 vw = vl[(HPOS(KK)<<2) + s]; \
    o0.x = fmaf(wgt, bf_lo(vw.x), o0.x); \
    o0.y = fmaf(wgt, bf_hi(vw.x), o0.y); \
    o0.z = fmaf(wgt, bf_lo(vw.y), o0.z); \
    o0.w = fmaf(wgt, bf_hi(vw.y), o0.w); \
    o1.x = fmaf(wgt, bf_lo(vw.z), o1.x); \
    o1.y = fmaf(wgt, bf_hi(vw.z), o1.y); \
    o1.z = fmaf(wgt, bf_lo(vw.w), o1.z); \
    o1.w = fmaf(wgt, bf_hi(vw.w), o1.w); }

    PVPOS(0,0)  PVPOS(1,1)  PVPOS(2,2)  PVPOS(3,3)  PVPOS(4,0)  PVPOS(5,1)  PVPOS(6,2)
    PVPOS(7,3)  PVPOS(8,0)  PVPOS(9,1)  PVPOS(10,2) PVPOS(11,3) PVPOS(12,0) PVPOS(13,1)
    PVPOS(14,2) PVPOS(15,3) PVPOS(16,0) PVPOS(17,1) PVPOS(18,2) PVPOS(19,3) PVPOS(20,0)
    PVPOS(21,1) PVPOS(22,2) PVPOS(23,3) PVPOS(24,0) PVPOS(25,1) PVPOS(26,2) PVPOS(27,3)
    PVPOS(28,0) PVPOS(29,1) PVPOS(30,2) PVPOS(31,3) PVPOS(32,0) PVPOS(33,1) PVPOS(34,2)
    PVPOS(35,3) PVPOS(36,0) PVPOS(37,1) PVPOS(38,2) PVPOS(39,3) PVPOS(40,0) PVPOS(41,1)
    PVPOS(42,2) PVPOS(43,3) PVPOS(44,0) PVPOS(45,1) PVPOS(46,2) PVPOS(47,3) PVPOS(48,0)

    float* aop = AO + ((size_t)b*N_ + n)*C_ + h*HD_ + s*8;
    o0.x *= inv; o0.y *= inv; o0.z *= inv; o0.w *= inv;
    o1.x *= inv; o1.y *= inv; o1.z *= inv; o1.w *= inv;
    ((float4*)aop)[0] = o0;
    ((float4*)aop)[1] = o1;
}

// ---------------------------------------------------------------------------
// Kernel 4: output projection (qkv_proj-style).
// ---------------------------------------------------------------------------
__global__ __launch_bounds__(256, 3) void out_proj(
    const float* __restrict__ AO, const float* __restrict__ Wo,
    const float* __restrict__ bo, float* __restrict__ out)
{
    __shared__ float4 ldsW4[64*32];   // 64 ci x 128 co (32 KB)
    __shared__ float  ldsX[128*32];   // [ci][pix] (16 KB)

    const int t  = threadIdx.x;
    const int b  = blockIdx.x / (N_/32);
    const int n0 = (blockIdx.x % (N_/32)) * 32;

    for (int idx = t; idx < 32*32; idx += 256) {
        int pix = idx & 31, c4 = idx >> 5;
        float4 v = ((const float4*)(AO + ((size_t)b*N_ + n0 + pix)*C_))[c4];
        ldsX[(c4*4+0)*32 + pix] = v.x;
        ldsX[(c4*4+1)*32 + pix] = v.y;
        ldsX[(c4*4+2)*32 + pix] = v.z;
        ldsX[(c4*4+3)*32 + pix] = v.w;
    }

    const int co_g  = t & 31;   // co = co_g*4 .. +3
    const int pix_g = t >> 5;   // pix = pix_g*4 .. +3

    float4 bias = *(const float4*)(bo + co_g*4);
    float4 acc0 = bias, acc1 = bias, acc2 = bias, acc3 = bias;
    for (int half = 0; half < 2; ++half) {
        __syncthreads();   // guards AO-stage (half 0) and ldsW readers (half 1)
        const float4* wsrc4 = (const float4*)(Wo + (size_t)half*64*C_);
        for (int idx = t; idx < 64*32; idx += 256) ldsW4[idx] = wsrc4[idx];
        __syncthreads();
        #pragma unroll 8
        for (int ci = 0; ci < 64; ++ci) {
            float4 xv = *(const float4*)(ldsX + (half*64 + ci)*32 + pix_g*4);
            float4 wv = ldsW4[ci*32 + co_g];
            fma4(acc0, xv.x, wv);
            fma4(acc1, xv.y, wv);
            fma4(acc2, xv.z, wv);
            fma4(acc3, xv.w, wv);
        }
    }
    float4 accs[4] = {acc0, acc1, acc2, acc3};
    #pragma unroll
    for (int p = 0; p < 4; ++p) {
        int n = n0 + pix_g*4 + p;
        size_t base = ((size_t)b*C_ + co_g*4)*N_ + n;
        out[base        ] = accs[p].x;
        out[base +   N_ ] = accs[p].y;
        out[base + 2*N_ ] = accs[p].z;
        out[base + 3*N_ ] = accs[p].w;
    }
}

// ---------------------------------------------------------------------------
extern "C" void kernel_launch(void* const* d_in, const int* in_sizes, int n_in,
                              void* d_out, int out_size, void* d_ws, size_t ws_size,
                              hipStream_t stream)
{
    const float* x    = (const float*)d_in[0];
    const float* phi  = (const float*)d_in[1];
    const float* Wq   = (const float*)d_in[2];
    const float* bq   = (const float*)d_in[3];
    const float* Wk   = (const float*)d_in[4];
    const float* bk   = (const float*)d_in[5];
    const float* Wv   = (const float*)d_in[6];
    const float* bv   = (const float*)d_in[7];
    const float* Wo   = (const float*)d_in[8];
    const float* bo   = (const float*)d_in[9];
    const float* la   = (const float*)d_in[10];
    const float* beta = (const float*)d_in[11];
    float* out = (float*)d_out;

    // workspace layout. AO aliases Qp: each attn thread reads exactly the q
    // slice it later writes as AO (same n, same head, same channels).
    float* ws   = (float*)d_ws;
    float* Qp   = ws;                                        // 9.44 MB
    uint*  KVp  = (uint*)(Qp + (size_t)B_*N_*C_);            // 10.65 MB
    float* PhiT = (float*)(KVp + (size_t)B_*HEADS_*HP2_*32); // 1.33 MB
    float* AO   = Qp;                                        // aliased

    pad_fill<<<dim3((B_*HP2_ + 255)/256), dim3(256), 0, stream>>>(phi, bk, bv, KVp, PhiT);
    qkv_proj<<<dim3(N_/32, B_, 3), dim3(256), 0, stream>>>(x, Wq, bq, Wk, bk, Wv, bv, Qp, KVp);
    attn<<<dim3((H_/TILE_)*(W_/TILE_), HEADS_, B_), dim3(256), 0, stream>>>(Qp, KVp, PhiT, la, beta, AO);
    out_proj<<<dim3(B_*(N_/32)), dim3(256), 0, stream>>>(AO, Wo, bo, out);
}

// Round 9
// 104.066 us; speedup vs baseline: 1.3981x; 1.3981x over previous
//
#include <hip/hip_runtime.h>

typedef unsigned int uint;

#define B_ 2
#define C_ 128
#define H_ 96
#define W_ 96
#define HEADS_ 4
#define HD_ 32
#define M_ 16
#define WIN_ 7
#define PAD_ 3
#define N_ (H_*W_)              // 9216
#define HP_ (H_+2*PAD_)         // 102
#define HP2_ (HP_*HP_)          // 10404
#define KW_ (WIN_*WIN_)         // 49
#define TILE_ 8                 // attn tile is 8x8 pixels
#define HALO_ (TILE_+WIN_-1)    // 14
#define NHALO_ (HALO_*HALO_)    // 196

static __device__ __forceinline__ uint f2bf(float f) {
    uint u = __float_as_uint(f);
    u = (u + 0x7fffu + ((u >> 16) & 1u)) >> 16;   // RNE to bf16
    return u & 0xffffu;
}
static __device__ __forceinline__ uint pack2(float a, float b) {
    return f2bf(a) | (f2bf(b) << 16);
}
static __device__ __forceinline__ float bf_lo(uint u){ return __uint_as_float(u << 16); }
static __device__ __forceinline__ float bf_hi(uint u){ return __uint_as_float(u & 0xffff0000u); }

// inline function, not a macro: macro params named w/x/y/z collide with
// float4 member access under preprocessor substitution.
static __device__ __forceinline__ void fma4(float4& acc, float s, const float4& v) {
    acc.x = fmaf(s, v.x, acc.x);
    acc.y = fmaf(s, v.y, acc.y);
    acc.z = fmaf(s, v.z, acc.z);
    acc.w = fmaf(s, v.w, acc.w);
}

// Intra-quad cross-lane via DPP quad_perm (VALU pipe) instead of __shfl_*.
template<int CTRL>
static __device__ __forceinline__ float dpp_mov(float v) {
    return __int_as_float(__builtin_amdgcn_update_dpp(
        0, __float_as_int(v), CTRL, 0xF, 0xF, false));
}
#define DPP_XOR1(v)  dpp_mov<0xB1>(v)   // [1,0,3,2]
#define DPP_XOR2(v)  dpp_mov<0x4E>(v)   // [2,3,0,1]
#define DPP_BCAST0(v) dpp_mov<0x00>(v)
#define DPP_BCAST1(v) dpp_mov<0x55>(v)
#define DPP_BCAST2(v) dpp_mov<0xAA>(v)
#define DPP_BCAST3(v) dpp_mov<0xFF>(v)

// ---------------------------------------------------------------------------
// KVp layout (head-major, K/V interleaved, bf16 pairs):
//   KVp[((b*HEADS+h)*HP2 + row)*32 + u], u<16: K pair u, u>=16: V pair u-16.
// ---------------------------------------------------------------------------

// Kernel 1: fill padded borders of KVp with bias (= proj of zero input), and
// build PhiT: [B][102][102][16] fp32, border = 1.0
__global__ __launch_bounds__(256) void pad_fill(
    const float* __restrict__ phi, const float* __restrict__ bk, const float* __restrict__ bv,
    uint* __restrict__ KVp, float* __restrict__ PhiT)
{
    int idx = blockIdx.x * 256 + threadIdx.x;
    if (idx >= B_*HP2_) return;
    int b  = idx / HP2_;
    int pp = idx % HP2_;
    int py = pp / HP_, px = pp % HP_;
    bool interior = (py >= PAD_ && py < H_+PAD_ && px >= PAD_ && px < W_+PAD_);
    if (!interior) {
        #pragma unroll
        for (int h = 0; h < HEADS_; ++h) {
            size_t base = ((size_t)(b*HEADS_+h)*HP2_ + pp) * 32;
            #pragma unroll
            for (int q4i = 0; q4i < 4; ++q4i) {
                const float* kb8 = bk + h*HD_ + q4i*8;
                const float* vb8 = bv + h*HD_ + q4i*8;
                uint4 ku, vu;
                ku.x = pack2(kb8[0],kb8[1]); ku.y = pack2(kb8[2],kb8[3]);
                ku.z = pack2(kb8[4],kb8[5]); ku.w = pack2(kb8[6],kb8[7]);
                vu.x = pack2(vb8[0],vb8[1]); vu.y = pack2(vb8[2],vb8[3]);
                vu.z = pack2(vb8[4],vb8[5]); vu.w = pack2(vb8[6],vb8[7]);
                ((uint4*)(KVp + base))[q4i]     = ku;
                ((uint4*)(KVp + base))[4 + q4i] = vu;
            }
        }
    }
    size_t pb = ((size_t)b*HP2_ + pp) * M_;
    if (interior) {
        int y = py - PAD_, xx = px - PAD_;
        #pragma unroll
        for (int m = 0; m < M_; ++m)
            PhiT[pb + m] = phi[((size_t)b*M_ + m)*N_ + y*W_ + xx];
    } else {
        #pragma unroll
        for (int m = 0; m < M_; ++m) PhiT[pb + m] = 1.0f;
    }
}

// ---------------------------------------------------------------------------
// Kernel 2: Q/K/V projection, one projection per block (grid.z = 0/1/2).
// ---------------------------------------------------------------------------
__global__ __launch_bounds__(256, 3) void qkv_proj(
    const float* __restrict__ x,
    const float* __restrict__ Wq, const float* __restrict__ bq,
    const float* __restrict__ Wk, const float* __restrict__ bk,
    const float* __restrict__ Wv, const float* __restrict__ bv,
    float* __restrict__ Qp, uint* __restrict__ KVp)
{
    __shared__ float4 ldsW4[64*32];   // 64 ci x 128 co (32 KB)
    __shared__ float4 ldsX4[128*8];   // [ci][pix] 128 x 32 (16 KB)

    const int t  = threadIdx.x;
    const int n0 = blockIdx.x * 32;
    const int b  = blockIdx.y;
    const int pj = blockIdx.z;
    const float* Wsrc = (pj == 0) ? Wq : (pj == 1) ? Wk : Wv;
    const float* bsrc = (pj == 0) ? bq : (pj == 1) ? bk : bv;

    for (int idx = t; idx < 128*32; idx += 256) {
        int pix = idx & 31, ci = idx >> 5;
        ((float*)ldsX4)[ci*32 + pix] = x[((size_t)b*C_ + ci)*N_ + n0 + pix];
    }

    const int co_g  = t & 31;   // co = co_g*4 .. +3
    const int pix_g = t >> 5;   // pix = pix_g*4 .. +3

    float4 bias = *(const float4*)(bsrc + co_g*4);
    float4 acc0 = bias, acc1 = bias, acc2 = bias, acc3 = bias;
    for (int half = 0; half < 2; ++half) {
        __syncthreads();   // guards x-stage (half 0) and ldsW readers (half 1)
        const float4* wsrc4 = (const float4*)(Wsrc + (size_t)half*64*C_);
        for (int idx = t; idx < 64*32; idx += 256) ldsW4[idx] = wsrc4[idx];
        __syncthreads();
        #pragma unroll 8
        for (int ci = 0; ci < 64; ++ci) {
            float4 xv = ldsX4[(half*64 + ci)*8 + pix_g];
            float4 wv = ldsW4[ci*32 + co_g];
            fma4(acc0, xv.x, wv);
            fma4(acc1, xv.y, wv);
            fma4(acc2, xv.z, wv);
            fma4(acc3, xv.w, wv);
        }
    }
    float4 accs[4] = {acc0, acc1, acc2, acc3};
    #pragma unroll
    for (int p = 0; p < 4; ++p) {
        int n = n0 + pix_g*4 + p;
        if (pj == 0) {
            *(float4*)(Qp + ((size_t)b*N_ + n)*C_ + co_g*4) = accs[p];
        } else {
            int y = n / W_, xx = n % W_;
            size_t rowb = (size_t)(y+PAD_)*HP_ + (xx+PAD_);
            int h = co_g >> 3;
            int u = ((pj == 1) ? 0 : 16) + (co_g & 7)*2;
            uint2 uu;
            uu.x = pack2(accs[p].x, accs[p].y);
            uu.y = pack2(accs[p].z, accs[p].w);
            *(uint2*)(KVp + ((size_t)(b*HEADS_+h)*HP2_ + rowb)*32 + u) = uu;
        }
    }
}

// ---------------------------------------------------------------------------
// Kernel 3: local attention, 4 threads per (pixel, head).
// K/V halo in LDS (24.5 KB -> 6 blocks/CU); phi read from GLOBAL (12.5 KB
// halo is L1-resident). launch_bounds(256,3): allocator free to use the
// natural ~90 VGPRs -- (256,5) in round 8 forced 48 VGPR and spilled 220MB.
// ---------------------------------------------------------------------------
__global__ __launch_bounds__(256, 3) void attn(
    const float* __restrict__ Qp, const uint* __restrict__ KVp,
    const float* __restrict__ PhiT, const float* __restrict__ log_alpha,
    const float* __restrict__ beta, float* __restrict__ AO)
{
    __shared__ uint4  kl[NHALO_*4];   // 12544 B
    __shared__ uint4  vl[NHALO_*4];   // 12544 B

    const int t  = threadIdx.x;
    const int h  = blockIdx.y;
    const int b  = blockIdx.z;
    const int bx = blockIdx.x;
    const int tile = ((bx & 7) * 18) + (bx >> 3);   // 144 = 8*18, bijective
    const int y0 = (tile / (W_/TILE_)) * TILE_;
    const int x0 = (tile % (W_/TILE_)) * TILE_;

    // stage K/V halo: one full 128B line per (row, head)
    const uint* kvb = KVp + (size_t)(b*HEADS_+h)*HP2_*32;
    for (int idx = t; idx < NHALO_*8; idx += 256) {
        int hp = idx >> 3, u4 = idx & 7;
        int hy = hp / HALO_, hx = hp % HALO_;
        size_t rowb = (size_t)(y0+hy)*HP_ + (x0+hx);
        uint4 val = *(const uint4*)(kvb + rowb*32 + u4*4);
        if (u4 < 4) kl[hp*4 + u4] = val;
        else        vl[hp*4 + (u4-4)] = val;
    }
    __syncthreads();

    const int s  = t & 3;       // sub-lane: channels s*8.., phi dims s*4..
    const int p  = t >> 2;      // pixel 0..63
    const int qy = p >> 3, qx = p & 7;
    const int n  = (y0+qy)*W_ + (x0+qx);
    const bool c1 = (s & 1) != 0;
    const bool c2 = (s & 2) != 0;

    float4 q0, q1;
    {
        const float* qptr = Qp + ((size_t)b*N_ + n)*C_ + h*HD_ + s*8;
        q0 = ((const float4*)qptr)[0];
        q1 = ((const float4*)qptr)[1];
    }
    // phi: center (exact) + window base pointer for this thread's quad slice
    const float* pwin = PhiT + ((size_t)b*HP2_ + (size_t)(y0+qy)*HP_ + (x0+qx))*M_ + s*4;
    float4 pc = *(const float4*)(pwin + ((size_t)PAD_*HP_ + PAD_)*M_);

    const float alpha = __expf(log_alpha[0]);
    const float scale = 0.17677669529663687f;                 // HD^-0.5
    const float gcoef = -beta[h] * alpha * 0.17677669529663687f; // -beta*alpha/sqrt(2M)

    auto partial = [&](int hp, const float4& pv) -> float {
        uint4 kw = kl[(hp<<2) + s];
        float4 acc = make_float4(0.f,0.f,0.f,0.f);
        acc.x = fmaf(q0.x, bf_lo(kw.x), acc.x);
        acc.y = fmaf(q0.y, bf_hi(kw.x), acc.y);
        acc.z = fmaf(q0.z, bf_lo(kw.y), acc.z);
        acc.w = fmaf(q0.w, bf_hi(kw.y), acc.w);
        acc.x = fmaf(q1.x, bf_lo(kw.z), acc.x);
        acc.y = fmaf(q1.y, bf_hi(kw.z), acc.y);
        acc.z = fmaf(q1.z, bf_lo(kw.w), acc.z);
        acc.w = fmaf(q1.w, bf_hi(kw.w), acc.w);
        float pdot = (acc.x + acc.y) + (acc.z + acc.w);
        float d0 = pc.x - pv.x, d1 = pc.y - pv.y;
        float d2 = pc.z - pv.z, d3 = pc.w - pv.w;
        float pdsq = fmaf(d0,d0, fmaf(d1,d1, fmaf(d2,d2, d3*d3)));
        return fmaf(pdot, scale, gcoef*pdsq);
    };

    float lp[13];
    float mx = -1e30f;

#define HPOS(KK) ((qy + (KK)/WIN_)*HALO_ + qx + ((KK)%WIN_))
#define PHV(KK) (*(const float4*)(pwin + (((KK)/WIN_)*HP_ + ((KK)%WIN_))*M_))
#define LGROUP(G) { \
    float pr0 = partial(HPOS(4*(G)  ), PHV(4*(G)  )); \
    float pr1 = partial(HPOS(4*(G)+1), PHV(4*(G)+1)); \
    float pr2 = partial(HPOS(4*(G)+2), PHV(4*(G)+2)); \
    float pr3 = partial(HPOS(4*(G)+3), PHV(4*(G)+3)); \
    float Av = (c1 ? pr1 : pr0) + DPP_XOR1(c1 ? pr0 : pr1); \
    float Bv = (c1 ? pr3 : pr2) + DPP_XOR1(c1 ? pr2 : pr3); \
    float lg = (c2 ? Bv : Av) + DPP_XOR2(c2 ? Av : Bv); \
    lp[(G)] = lg; mx = fmaxf(mx, lg); }

    LGROUP(0) LGROUP(1) LGROUP(2) LGROUP(3) LGROUP(4) LGROUP(5)
    LGROUP(6) LGROUP(7) LGROUP(8) LGROUP(9) LGROUP(10) LGROUP(11)
    {   // kk = 48: all lanes hold it; only lane s==0 "owns" it
        float pr = partial(HPOS(48), PHV(48));
        pr += DPP_XOR1(pr);
        pr += DPP_XOR2(pr);
        lp[12] = pr; mx = fmaxf(mx, pr);
    }
    mx = fmaxf(mx, DPP_XOR1(mx));
    mx = fmaxf(mx, DPP_XOR2(mx));

    float ssum = 0.f;
#define EXPG(G) { float e = __expf(lp[(G)] - mx); lp[(G)] = e; ssum += e; }
    EXPG(0) EXPG(1) EXPG(2) EXPG(3) EXPG(4) EXPG(5)
    EXPG(6) EXPG(7) EXPG(8) EXPG(9) EXPG(10) EXPG(11)
    {
        float e = (s == 0) ? __expf(lp[12] - mx) : 0.f;
        lp[12] = e; ssum += e;
    }
    ssum += DPP_XOR1(ssum);
    ssum += DPP_XOR2(ssum);
    float inv = 1.0f / ssum;

    float4 o0 = make_float4(0.f,0.f,0.f,0.f);
    float4 o1 = make_float4(0.f,0.f,0.f,0.f);
#define PVPOS(KK, BC) { \
    float wgt = DPP_BCAST##BC(lp[(KK)>>2]); \
    uint4 vw = vl[(HPOS(KK)<<2) + s]; \
    o0.x = fmaf(wgt, bf_lo(vw.x), o0.x); \
    o0.y = fmaf(wgt, bf_hi(vw.x), o0.y); \
    o0.z = fmaf(wgt, bf_lo(vw.y), o0.z); \
    o0.w = fmaf(wgt, bf_hi(vw.y), o0.w); \
    o1.x = fmaf(wgt, bf_lo(vw.z), o1.x); \
    o1.y = fmaf(wgt, bf_hi(vw.z), o1.y); \
    o1.z = fmaf(wgt, bf_lo(vw.w), o1.z); \
    o1.w = fmaf(wgt, bf_hi(vw.w), o1.w); }

    PVPOS(0,0)  PVPOS(1,1)  PVPOS(2,2)  PVPOS(3,3)  PVPOS(4,0)  PVPOS(5,1)  PVPOS(6,2)
    PVPOS(7,3)  PVPOS(8,0)  PVPOS(9,1)  PVPOS(10,2) PVPOS(11,3) PVPOS(12,0) PVPOS(13,1)
    PVPOS(14,2) PVPOS(15,3) PVPOS(16,0) PVPOS(17,1) PVPOS(18,2) PVPOS(19,3) PVPOS(20,0)
    PVPOS(21,1) PVPOS(22,2) PVPOS(23,3) PVPOS(24,0) PVPOS(25,1) PVPOS(26,2) PVPOS(27,3)
    PVPOS(28,0) PVPOS(29,1) PVPOS(30,2) PVPOS(31,3) PVPOS(32,0) PVPOS(33,1) PVPOS(34,2)
    PVPOS(35,3) PVPOS(36,0) PVPOS(37,1) PVPOS(38,2) PVPOS(39,3) PVPOS(40,0) PVPOS(41,1)
    PVPOS(42,2) PVPOS(43,3) PVPOS(44,0) PVPOS(45,1) PVPOS(46,2) PVPOS(47,3) PVPOS(48,0)

    float* aop = AO + ((size_t)b*N_ + n)*C_ + h*HD_ + s*8;
    o0.x *= inv; o0.y *= inv; o0.z *= inv; o0.w *= inv;
    o1.x *= inv; o1.y *= inv; o1.z *= inv; o1.w *= inv;
    ((float4*)aop)[0] = o0;
    ((float4*)aop)[1] = o1;
}

// ---------------------------------------------------------------------------
// Kernel 4: output projection (qkv_proj-style).
// ---------------------------------------------------------------------------
__global__ __launch_bounds__(256, 3) void out_proj(
    const float* __restrict__ AO, const float* __restrict__ Wo,
    const float* __restrict__ bo, float* __restrict__ out)
{
    __shared__ float4 ldsW4[64*32];   // 64 ci x 128 co (32 KB)
    __shared__ float  ldsX[128*32];   // [ci][pix] (16 KB)

    const int t  = threadIdx.x;
    const int b  = blockIdx.x / (N_/32);
    const int n0 = (blockIdx.x % (N_/32)) * 32;

    for (int idx = t; idx < 32*32; idx += 256) {
        int pix = idx & 31, c4 = idx >> 5;
        float4 v = ((const float4*)(AO + ((size_t)b*N_ + n0 + pix)*C_))[c4];
        ldsX[(c4*4+0)*32 + pix] = v.x;
        ldsX[(c4*4+1)*32 + pix] = v.y;
        ldsX[(c4*4+2)*32 + pix] = v.z;
        ldsX[(c4*4+3)*32 + pix] = v.w;
    }

    const int co_g  = t & 31;   // co = co_g*4 .. +3
    const int pix_g = t >> 5;   // pix = pix_g*4 .. +3

    float4 bias = *(const float4*)(bo + co_g*4);
    float4 acc0 = bias, acc1 = bias, acc2 = bias, acc3 = bias;
    for (int half = 0; half < 2; ++half) {
        __syncthreads();   // guards AO-stage (half 0) and ldsW readers (half 1)
        const float4* wsrc4 = (const float4*)(Wo + (size_t)half*64*C_);
        for (int idx = t; idx < 64*32; idx += 256) ldsW4[idx] = wsrc4[idx];
        __syncthreads();
        #pragma unroll 8
        for (int ci = 0; ci < 64; ++ci) {
            float4 xv = *(const float4*)(ldsX + (half*64 + ci)*32 + pix_g*4);
            float4 wv = ldsW4[ci*32 + co_g];
            fma4(acc0, xv.x, wv);
            fma4(acc1, xv.y, wv);
            fma4(acc2, xv.z, wv);
            fma4(acc3, xv.w, wv);
        }
    }
    float4 accs[4] = {acc0, acc1, acc2, acc3};
    #pragma unroll
    for (int p = 0; p < 4; ++p) {
        int n = n0 + pix_g*4 + p;
        size_t base = ((size_t)b*C_ + co_g*4)*N_ + n;
        out[base        ] = accs[p].x;
        out[base +   N_ ] = accs[p].y;
        out[base + 2*N_ ] = accs[p].z;
        out[base + 3*N_ ] = accs[p].w;
    }
}

// ---------------------------------------------------------------------------
extern "C" void kernel_launch(void* const* d_in, const int* in_sizes, int n_in,
                              void* d_out, int out_size, void* d_ws, size_t ws_size,
                              hipStream_t stream)
{
    const float* x    = (const float*)d_in[0];
    const float* phi  = (const float*)d_in[1];
    const float* Wq   = (const float*)d_in[2];
    const float* bq   = (const float*)d_in[3];
    const float* Wk   = (const float*)d_in[4];
    const float* bk   = (const float*)d_in[5];
    const float* Wv   = (const float*)d_in[6];
    const float* bv   = (const float*)d_in[7];
    const float* Wo   = (const float*)d_in[8];
    const float* bo   = (const float*)d_in[9];
    const float* la   = (const float*)d_in[10];
    const float* beta = (const float*)d_in[11];
    float* out = (float*)d_out;

    // workspace layout. AO aliases Qp: each attn thread reads exactly the q
    // slice it later writes as AO (same n, same head, same channels).
    float* ws   = (float*)d_ws;
    float* Qp   = ws;                                        // 9.44 MB
    uint*  KVp  = (uint*)(Qp + (size_t)B_*N_*C_);            // 10.65 MB
    float* PhiT = (float*)(KVp + (size_t)B_*HEADS_*HP2_*32); // 1.33 MB
    float* AO   = Qp;                                        // aliased

    pad_fill<<<dim3((B_*HP2_ + 255)/256), dim3(256), 0, stream>>>(phi, bk, bv, KVp, PhiT);
    qkv_proj<<<dim3(N_/32, B_, 3), dim3(256), 0, stream>>>(x, Wq, bq, Wk, bk, Wv, bv, Qp, KVp);
    attn<<<dim3((H_/TILE_)*(W_/TILE_), HEADS_, B_), dim3(256), 0, stream>>>(Qp, KVp, PhiT, la, beta, AO);
    out_proj<<<dim3(B_*(N_/32)), dim3(256), 0, stream>>>(AO, Wo, bo, out);
}

// Round 11
// 83.043 us; speedup vs baseline: 1.7520x; 1.2532x over previous
//
#include <hip/hip_runtime.h>

typedef unsigned int uint;

#define B_ 2
#define C_ 128
#define H_ 96
#define W_ 96
#define HEADS_ 4
#define HD_ 32
#define M_ 16
#define WIN_ 7
#define PAD_ 3
#define N_ (H_*W_)              // 9216
#define HP_ (H_+2*PAD_)         // 102
#define HP2_ (HP_*HP_)          // 10404
#define KW_ (WIN_*WIN_)         // 49
#define TILE_ 8                 // attn tile is 8x8 pixels
#define HALO_ (TILE_+WIN_-1)    // 14
#define NHALO_ (HALO_*HALO_)    // 196

static __device__ __forceinline__ uint f2bf(float f) {
    uint u = __float_as_uint(f);
    u = (u + 0x7fffu + ((u >> 16) & 1u)) >> 16;   // RNE to bf16 (integer, mode-independent)
    return u & 0xffffu;
}
static __device__ __forceinline__ uint pack2(float a, float b) {
    return f2bf(a) | (f2bf(b) << 16);
}
static __device__ __forceinline__ float bf_lo(uint u){ return __uint_as_float(u << 16); }
static __device__ __forceinline__ float bf_hi(uint u){ return __uint_as_float(u & 0xffff0000u); }

// inline function, not a macro: macro params named w/x/y/z collide with
// float4 member access under preprocessor substitution.
static __device__ __forceinline__ void fma4(float4& acc, float s, const float4& v) {
    acc.x = fmaf(s, v.x, acc.x);
    acc.y = fmaf(s, v.y, acc.y);
    acc.z = fmaf(s, v.z, acc.z);
    acc.w = fmaf(s, v.w, acc.w);
}

// HW bf16 pair-dot: D = a.bf16[0]*b.bf16[0] + a.bf16[1]*b.bf16[1] + c  (1 inst)
static __device__ __forceinline__ float dot2bf(uint a, uint b, float c) {
    float d;
    asm("v_dot2_f32_bf16 %0, %1, %2, %3" : "=v"(d) : "v"(a), "v"(b), "v"(c));
    return d;
}

// Intra-quad cross-lane via DPP quad_perm (VALU pipe) instead of __shfl_*.
template<int CTRL>
static __device__ __forceinline__ float dpp_mov(float v) {
    return __int_as_float(__builtin_amdgcn_update_dpp(
        0, __float_as_int(v), CTRL, 0xF, 0xF, false));
}
#define DPP_XOR1(v)  dpp_mov<0xB1>(v)   // [1,0,3,2]
#define DPP_XOR2(v)  dpp_mov<0x4E>(v)   // [2,3,0,1]
#define DPP_BCAST0(v) dpp_mov<0x00>(v)
#define DPP_BCAST1(v) dpp_mov<0x55>(v)
#define DPP_BCAST2(v) dpp_mov<0xAA>(v)
#define DPP_BCAST3(v) dpp_mov<0xFF>(v)

// ---------------------------------------------------------------------------
// KVp layout (head-major, K/V interleaved, bf16 pairs):
//   KVp[((b*HEADS+h)*HP2 + row)*32 + u], u<16: K pair u, u>=16: V pair u-16.
// ---------------------------------------------------------------------------

// Kernel 1: fill padded borders of KVp with bias (= proj of zero input), and
// build PhiT: [B][102][102][16] fp32, border = 1.0
__global__ __launch_bounds__(256) void pad_fill(
    const float* __restrict__ phi, const float* __restrict__ bk, const float* __restrict__ bv,
    uint* __restrict__ KVp, float* __restrict__ PhiT)
{
    int idx = blockIdx.x * 256 + threadIdx.x;
    if (idx >= B_*HP2_) return;
    int b  = idx / HP2_;
    int pp = idx % HP2_;
    int py = pp / HP_, px = pp % HP_;
    bool interior = (py >= PAD_ && py < H_+PAD_ && px >= PAD_ && px < W_+PAD_);
    if (!interior) {
        #pragma unroll
        for (int h = 0; h < HEADS_; ++h) {
            size_t base = ((size_t)(b*HEADS_+h)*HP2_ + pp) * 32;
            #pragma unroll
            for (int q4i = 0; q4i < 4; ++q4i) {
                const float* kb8 = bk + h*HD_ + q4i*8;
                const float* vb8 = bv + h*HD_ + q4i*8;
                uint4 ku, vu;
                ku.x = pack2(kb8[0],kb8[1]); ku.y = pack2(kb8[2],kb8[3]);
                ku.z = pack2(kb8[4],kb8[5]); ku.w = pack2(kb8[6],kb8[7]);
                vu.x = pack2(vb8[0],vb8[1]); vu.y = pack2(vb8[2],vb8[3]);
                vu.z = pack2(vb8[4],vb8[5]); vu.w = pack2(vb8[6],vb8[7]);
                ((uint4*)(KVp + base))[q4i]     = ku;
                ((uint4*)(KVp + base))[4 + q4i] = vu;
            }
        }
    }
    size_t pb = ((size_t)b*HP2_ + pp) * M_;
    if (interior) {
        int y = py - PAD_, xx = px - PAD_;
        #pragma unroll
        for (int m = 0; m < M_; ++m)
            PhiT[pb + m] = phi[((size_t)b*M_ + m)*N_ + y*W_ + xx];
    } else {
        #pragma unroll
        for (int m = 0; m < M_; ++m) PhiT[pb + m] = 1.0f;
    }
}

// ---------------------------------------------------------------------------
// Kernel 2: Q/K/V projection, one projection per block (grid.z = 0/1/2).
// ---------------------------------------------------------------------------
__global__ __launch_bounds__(256, 3) void qkv_proj(
    const float* __restrict__ x,
    const float* __restrict__ Wq, const float* __restrict__ bq,
    const float* __restrict__ Wk, const float* __restrict__ bk,
    const float* __restrict__ Wv, const float* __restrict__ bv,
    float* __restrict__ Qp, uint* __restrict__ KVp)
{
    __shared__ float4 ldsW4[64*32];   // 64 ci x 128 co (32 KB)
    __shared__ float4 ldsX4[128*8];   // [ci][pix] 128 x 32 (16 KB)

    const int t  = threadIdx.x;
    const int n0 = blockIdx.x * 32;
    const int b  = blockIdx.y;
    const int pj = blockIdx.z;
    const float* Wsrc = (pj == 0) ? Wq : (pj == 1) ? Wk : Wv;
    const float* bsrc = (pj == 0) ? bq : (pj == 1) ? bk : bv;

    for (int idx = t; idx < 128*32; idx += 256) {
        int pix = idx & 31, ci = idx >> 5;
        ((float*)ldsX4)[ci*32 + pix] = x[((size_t)b*C_ + ci)*N_ + n0 + pix];
    }

    const int co_g  = t & 31;   // co = co_g*4 .. +3
    const int pix_g = t >> 5;   // pix = pix_g*4 .. +3

    float4 bias = *(const float4*)(bsrc + co_g*4);
    float4 acc0 = bias, acc1 = bias, acc2 = bias, acc3 = bias;
    for (int half = 0; half < 2; ++half) {
        __syncthreads();   // guards x-stage (half 0) and ldsW readers (half 1)
        const float4* wsrc4 = (const float4*)(Wsrc + (size_t)half*64*C_);
        for (int idx = t; idx < 64*32; idx += 256) ldsW4[idx] = wsrc4[idx];
        __syncthreads();
        #pragma unroll 8
        for (int ci = 0; ci < 64; ++ci) {
            float4 xv = ldsX4[(half*64 + ci)*8 + pix_g];
            float4 wv = ldsW4[ci*32 + co_g];
            fma4(acc0, xv.x, wv);
            fma4(acc1, xv.y, wv);
            fma4(acc2, xv.z, wv);
            fma4(acc3, xv.w, wv);
        }
    }
    float4 accs[4] = {acc0, acc1, acc2, acc3};
    #pragma unroll
    for (int p = 0; p < 4; ++p) {
        int n = n0 + pix_g*4 + p;
        if (pj == 0) {
            *(float4*)(Qp + ((size_t)b*N_ + n)*C_ + co_g*4) = accs[p];
        } else {
            int y = n / W_, xx = n % W_;
            size_t rowb = (size_t)(y+PAD_)*HP_ + (xx+PAD_);
            int h = co_g >> 3;
            int u = ((pj == 1) ? 0 : 16) + (co_g & 7)*2;
            uint2 uu;
            uu.x = pack2(accs[p].x, accs[p].y);
            uu.y = pack2(accs[p].z, accs[p].w);
            *(uint2*)(KVp + ((size_t)(b*HEADS_+h)*HP2_ + rowb)*32 + u) = uu;
        }
    }
}

// ---------------------------------------------------------------------------
// Kernel 3: local attention, 4 threads per (pixel, head).
// QK on v_dot2_f32_bf16 with COMPENSATED q: q = q_hi(bf16,RNE) + q_lo(bf16 of
// residual), both packed by integer RNE (mode-independent). q-side error
// ~2^-17 rel -> logit error = k-rounding only (round-7 budget, 3x margin).
// Each partial: 1 ds_read_b128 + two 4-deep dot2 chains + 1 add.
// ---------------------------------------------------------------------------
__global__ __launch_bounds__(256, 3) void attn(
    const float* __restrict__ Qp, const uint* __restrict__ KVp,
    const float* __restrict__ PhiT, const float* __restrict__ log_alpha,
    const float* __restrict__ beta, float* __restrict__ AO)
{
    __shared__ uint4  kl[NHALO_*4];   // 12544 B
    __shared__ uint4  vl[NHALO_*4];   // 12544 B
    __shared__ float4 pl[NHALO_*4];   // 12544 B

    const int t  = threadIdx.x;
    const int h  = blockIdx.y;
    const int b  = blockIdx.z;
    const int bx = blockIdx.x;
    const int tile = ((bx & 7) * 18) + (bx >> 3);   // 144 = 8*18, bijective
    const int y0 = (tile / (W_/TILE_)) * TILE_;
    const int x0 = (tile % (W_/TILE_)) * TILE_;

    // stage K/V halo: one full 128B line per (row, head)
    const uint* kvb = KVp + (size_t)(b*HEADS_+h)*HP2_*32;
    for (int idx = t; idx < NHALO_*8; idx += 256) {
        int hp = idx >> 3, u4 = idx & 7;
        int hy = hp / HALO_, hx = hp % HALO_;
        size_t rowb = (size_t)(y0+hy)*HP_ + (x0+hx);
        uint4 val = *(const uint4*)(kvb + rowb*32 + u4*4);
        if (u4 < 4) kl[hp*4 + u4] = val;
        else        vl[hp*4 + (u4-4)] = val;
    }
    // stage phi halo (fp32)
    const float* pbase = PhiT + (size_t)b*HP2_*M_;
    for (int idx = t; idx < NHALO_*4; idx += 256) {
        int hp = idx >> 2, sb = idx & 3;
        int hy = hp / HALO_, hx = hp % HALO_;
        size_t rowb = (size_t)(y0+hy)*HP_ + (x0+hx);
        pl[idx] = *(const float4*)(pbase + rowb*M_ + sb*4);
    }
    __syncthreads();

    const int s  = t & 3;       // sub-lane: channels s*8.., phi dims s*4..
    const int p  = t >> 2;      // pixel 0..63
    const int qy = p >> 3, qx = p & 7;
    const int n  = (y0+qy)*W_ + (x0+qx);
    const bool c1 = (s & 1) != 0;
    const bool c2 = (s & 2) != 0;

    // q: load fp32; split q = q_hi + q_lo (both bf16, integer RNE pack).
    uint qh0, qh1, qh2, qh3, ql0, ql1, ql2, ql3;
    {
        const float* qptr = Qp + ((size_t)b*N_ + n)*C_ + h*HD_ + s*8;
        float4 q0 = ((const float4*)qptr)[0];
        float4 q1 = ((const float4*)qptr)[1];
        float qf[8] = {q0.x, q0.y, q0.z, q0.w, q1.x, q1.y, q1.z, q1.w};
        float rf[8];
        #pragma unroll
        for (int i = 0; i < 8; ++i)
            rf[i] = qf[i] - __uint_as_float(f2bf(qf[i]) << 16);
        qh0 = pack2(qf[0], qf[1]); qh1 = pack2(qf[2], qf[3]);
        qh2 = pack2(qf[4], qf[5]); qh3 = pack2(qf[6], qf[7]);
        ql0 = pack2(rf[0], rf[1]); ql1 = pack2(rf[2], rf[3]);
        ql2 = pack2(rf[4], rf[5]); ql3 = pack2(rf[6], rf[7]);
    }
    float4 pc = pl[((qy+PAD_)*HALO_ + (qx+PAD_))*4 + s];

    const float alpha = __expf(log_alpha[0]);
    const float scale = 0.17677669529663687f;                 // HD^-0.5
    const float gcoef = -beta[h] * alpha * 0.17677669529663687f; // -beta*alpha/sqrt(2M)

    auto partial = [&](int hp) -> float {
        uint4 kw = kl[(hp<<2) + s];
        float da = dot2bf(qh0, kw.x, 0.0f);
        float db = dot2bf(ql0, kw.x, 0.0f);
        da = dot2bf(qh1, kw.y, da);
        db = dot2bf(ql1, kw.y, db);
        da = dot2bf(qh2, kw.z, da);
        db = dot2bf(ql2, kw.z, db);
        da = dot2bf(qh3, kw.w, da);
        db = dot2bf(ql3, kw.w, db);
        float pdot = da + db;
        float4 pv = pl[(hp<<2) + s];
        float d0 = pc.x - pv.x, d1 = pc.y - pv.y;
        float d2 = pc.z - pv.z, d3 = pc.w - pv.w;
        float pdsq = fmaf(d0,d0, fmaf(d1,d1, fmaf(d2,d2, d3*d3)));
        return fmaf(pdot, scale, gcoef*pdsq);
    };

    float lp[13];
    float mx = -1e30f;

#define HPOS(KK) ((qy + (KK)/WIN_)*HALO_ + qx + ((KK)%WIN_))
#define LGROUP(G) { \
    float pr0 = partial(HPOS(4*(G)  )); \
    float pr1 = partial(HPOS(4*(G)+1)); \
    float pr2 = partial(HPOS(4*(G)+2)); \
    float pr3 = partial(HPOS(4*(G)+3)); \
    float Av = (c1 ? pr1 : pr0) + DPP_XOR1(c1 ? pr0 : pr1); \
    float Bv = (c1 ? pr3 : pr2) + DPP_XOR1(c1 ? pr2 : pr3); \
    float lg = (c2 ? Bv : Av) + DPP_XOR2(c2 ? Av : Bv); \
    lp[(G)] = lg; mx = fmaxf(mx, lg); }

    LGROUP(0) LGROUP(1) LGROUP(2) LGROUP(3) LGROUP(4) LGROUP(5)
    LGROUP(6) LGROUP(7) LGROUP(8) LGROUP(9) LGROUP(10) LGROUP(11)
    {   // kk = 48: all lanes hold it; only lane s==0 "owns" it
        float pr = partial(HPOS(48));
        pr += DPP_XOR1(pr);
        pr += DPP_XOR2(pr);
        lp[12] = pr; mx = fmaxf(mx, pr);
    }
    mx = fmaxf(mx, DPP_XOR1(mx));
    mx = fmaxf(mx, DPP_XOR2(mx));

    float ssum = 0.f;
#define EXPG(G) { float e = __expf(lp[(G)] - mx); lp[(G)] = e; ssum += e; }
    EXPG(0) EXPG(1) EXPG(2) EXPG(3) EXPG(4) EXPG(5)
    EXPG(6) EXPG(7) EXPG(8) EXPG(9) EXPG(10) EXPG(11)
    {
        float e = (s == 0) ? __expf(lp[12] - mx) : 0.f;
        lp[12] = e; ssum += e;
    }
    ssum += DPP_XOR1(ssum);
    ssum += DPP_XOR2(ssum);
    float inv = 1.0f / ssum;

    float4 o0 = make_float4(0.f,0.f,0.f,0.f);
    float4 o1 = make_float4(0.f,0.f,0.f,0.f);
#define PVPOS(KK, BC) { \
    float wgt = DPP_BCAST##BC(lp[(KK)>>2]); \
    uint4 vw = vl[(HPOS(KK)<<2) + s]; \
    o0.x = fmaf(wgt, bf_lo(vw.x), o0.x); \
    o0.y = fmaf(wgt, bf_hi(vw.x), o0.y); \
    o0.z = fmaf(wgt, bf_lo(vw.y), o0.z); \
    o0.w = fmaf(wgt, bf_hi(vw.y), o0.w); \
    o1.x = fmaf(wgt, bf_lo(vw.z), o1.x); \
    o1.y = fmaf(wgt, bf_hi(vw.z), o1.y); \
    o1.z = fmaf(wgt, bf_lo(vw.w), o1.z); \
    o1.w = fmaf(wgt, bf_hi(vw.w), o1.w); }

    PVPOS(0,0)  PVPOS(1,1)  PVPOS(2,2)  PVPOS(3,3)  PVPOS(4,0)  PVPOS(5,1)  PVPOS(6,2)
    PVPOS(7,3)  PVPOS(8,0)  PVPOS(9,1)  PVPOS(10,2) PVPOS(11,3) PVPOS(12,0) PVPOS(13,1)
    PVPOS(14,2) PVPOS(15,3) PVPOS(16,0) PVPOS(17,1) PVPOS(18,2) PVPOS(19,3) PVPOS(20,0)
    PVPOS(21,1) PVPOS(22,2) PVPOS(23,3) PVPOS(24,0) PVPOS(25,1) PVPOS(26,2) PVPOS(27,3)
    PVPOS(28,0) PVPOS(29,1) PVPOS(30,2) PVPOS(31,3) PVPOS(32,0) PVPOS(33,1) PVPOS(34,2)
    PVPOS(35,3) PVPOS(36,0) PVPOS(37,1) PVPOS(38,2) PVPOS(39,3) PVPOS(40,0) PVPOS(41,1)
    PVPOS(42,2) PVPOS(43,3) PVPOS(44,0) PVPOS(45,1) PVPOS(46,2) PVPOS(47,3) PVPOS(48,0)

    float* aop = AO + ((size_t)b*N_ + n)*C_ + h*HD_ + s*8;
    o0.x *= inv; o0.y *= inv; o0.z *= inv; o0.w *= inv;
    o1.x *= inv; o1.y *= inv; o1.z *= inv; o1.w *= inv;
    ((float4*)aop)[0] = o0;
    ((float4*)aop)[1] = o1;
}

// ---------------------------------------------------------------------------
// Kernel 4: output projection (qkv_proj-style).
// ---------------------------------------------------------------------------
__global__ __launch_bounds__(256, 3) void out_proj(
    const float* __restrict__ AO, const float* __restrict__ Wo,
    const float* __restrict__ bo, float* __restrict__ out)
{
    __shared__ float4 ldsW4[64*32];   // 64 ci x 128 co (32 KB)
    __shared__ float  ldsX[128*32];   // [ci][pix] (16 KB)

    const int t  = threadIdx.x;
    const int b  = blockIdx.x / (N_/32);
    const int n0 = (blockIdx.x % (N_/32)) * 32;

    for (int idx = t; idx < 32*32; idx += 256) {
        int pix = idx & 31, c4 = idx >> 5;
        float4 v = ((const float4*)(AO + ((size_t)b*N_ + n0 + pix)*C_))[c4];
        ldsX[(c4*4+0)*32 + pix] = v.x;
        ldsX[(c4*4+1)*32 + pix] = v.y;
        ldsX[(c4*4+2)*32 + pix] = v.z;
        ldsX[(c4*4+3)*32 + pix] = v.w;
    }

    const int co_g  = t & 31;   // co = co_g*4 .. +3
    const int pix_g = t >> 5;   // pix = pix_g*4 .. +3

    float4 bias = *(const float4*)(bo + co_g*4);
    float4 acc0 = bias, acc1 = bias, acc2 = bias, acc3 = bias;
    for (int half = 0; half < 2; ++half) {
        __syncthreads();   // guards AO-stage (half 0) and ldsW readers (half 1)
        const float4* wsrc4 = (const float4*)(Wo + (size_t)half*64*C_);
        for (int idx = t; idx < 64*32; idx += 256) ldsW4[idx] = wsrc4[idx];
        __syncthreads();
        #pragma unroll 8
        for (int ci = 0; ci < 64; ++ci) {
            float4 xv = *(const float4*)(ldsX + (half*64 + ci)*32 + pix_g*4);
            float4 wv = ldsW4[ci*32 + co_g];
            fma4(acc0, xv.x, wv);
            fma4(acc1, xv.y, wv);
            fma4(acc2, xv.z, wv);
            fma4(acc3, xv.w, wv);
        }
    }
    float4 accs[4] = {acc0, acc1, acc2, acc3};
    #pragma unroll
    for (int p = 0; p < 4; ++p) {
        int n = n0 + pix_g*4 + p;
        size_t base = ((size_t)b*C_ + co_g*4)*N_ + n;
        out[base        ] = accs[p].x;
        out[base +   N_ ] = accs[p].y;
        out[base + 2*N_ ] = accs[p].z;
        out[base + 3*N_ ] = accs[p].w;
    }
}

// ---------------------------------------------------------------------------
extern "C" void kernel_launch(void* const* d_in, const int* in_sizes, int n_in,
                              void* d_out, int out_size, void* d_ws, size_t ws_size,
                              hipStream_t stream)
{
    const float* x    = (const float*)d_in[0];
    const float* phi  = (const float*)d_in[1];
    const float* Wq   = (const float*)d_in[2];
    const float* bq   = (const float*)d_in[3];
    const float* Wk   = (const float*)d_in[4];
    const float* bk   = (const float*)d_in[5];
    const float* Wv   = (const float*)d_in[6];
    const float* bv   = (const float*)d_in[7];
    const float* Wo   = (const float*)d_in[8];
    const float* bo   = (const float*)d_in[9];
    const float* la   = (const float*)d_in[10];
    const float* beta = (const float*)d_in[11];
    float* out = (float*)d_out;

    // workspace layout. AO aliases Qp: each attn thread reads exactly the q
    // slice it later writes as AO (same n, same head, same channels).
    float* ws   = (float*)d_ws;
    float* Qp   = ws;                                        // 9.44 MB
    uint*  KVp  = (uint*)(Qp + (size_t)B_*N_*C_);            // 10.65 MB
    float* PhiT = (float*)(KVp + (size_t)B_*HEADS_*HP2_*32); // 1.33 MB
    float* AO   = Qp;                                        // aliased

    pad_fill<<<dim3((B_*HP2_ + 255)/256), dim3(256), 0, stream>>>(phi, bk, bv, KVp, PhiT);
    qkv_proj<<<dim3(N_/32, B_, 3), dim3(256), 0, stream>>>(x, Wq, bq, Wk, bk, Wv, bv, Qp, KVp);
    attn<<<dim3((H_/TILE_)*(W_/TILE_), HEADS_, B_), dim3(256), 0, stream>>>(Qp, KVp, PhiT, la, beta, AO);
    out_proj<<<dim3(B_*(N_/32)), dim3(256), 0, stream>>>(AO, Wo, bo, out);
}